// Round 11
// baseline (755.634 us; speedup 1.0000x reference)
//
#include <hip/hip_runtime.h>
#include <hip/hip_fp16.h>
#include <math.h>

#define FM 32
#define N_EDGES 3200000
#define VAR_COUNT 100000
#define CONST_COUNT 50000
#define LN_EPS 1e-5f

#define EPB 4096                 // edges per sort block
#define ABLK 782                 // ceil(N_EDGES / EPB)
#define HABLK 391                // sort blocks per half
#define NB 782                   // buckets (64 consts or 128 vars each)
#define AB2 784                  // padded stride for transposed rlen matrix
#define LSTRIDE 784              // NB + 2
#define CAPH 2560                // max records per half-bucket in LDS (+11 sigma)

static __device__ __forceinline__ float warp_sum32(float v) {
#pragma unroll
    for (int m = 16; m; m >>= 1) v += __shfl_xor(v, m);
    return v;
}

__global__ void init_vars(float* __restrict__ v, int n) {
    int i = blockIdx.x * 256 + threadIdx.x;
    if (i < n) v[i] = 1.0f;
}

// ---------------- block-local bucket sort (no global atomics) ----------------

template <int DSHIFT>
__global__ __launch_bounds__(256) void bucket_sort(
    const int* __restrict__ dest_arr, const int* __restrict__ src_arr,
    const float* __restrict__ val_arr,
    int2* __restrict__ recs_tmp, int* __restrict__ lscan, int* __restrict__ rlen_T,
    int n) {
    __shared__ int hist[NB];
    __shared__ int cursor[NB];
    __shared__ int chunk[256];
    __shared__ int2 stage[EPB];
    const int t = threadIdx.x;
    const int base = blockIdx.x * EPB;
    const int nb = min(EPB, n - base);
    for (int i = t; i < NB; i += 256) hist[i] = 0;
    __syncthreads();
    int dg[16], pk[16], vb[16];
#pragma unroll
    for (int k = 0; k < 16; ++k) {
        int j = k * 256 + t;
        dg[k] = -1;
        if (j < nb) {
            int dest = dest_arr[base + j];
            int src  = src_arr[base + j];
            vb[k] = __float_as_int(val_arr[base + j]);
            dg[k] = dest >> DSHIFT;
            pk[k] = ((dest & ((1 << DSHIFT) - 1)) << 20) | src;
            atomicAdd(&hist[dg[k]], 1);
        }
    }
    __syncthreads();
    int sum = 0;
#pragma unroll
    for (int k = 0; k < 4; ++k) {
        int idx = t * 4 + k;
        if (idx < NB) sum += hist[idx];
    }
    chunk[t] = sum;
    __syncthreads();
    for (int off = 1; off < 256; off <<= 1) {
        int v = (t >= off) ? chunk[t - off] : 0;
        __syncthreads();
        chunk[t] += v;
        __syncthreads();
    }
    int run = chunk[t] - sum;
#pragma unroll
    for (int k = 0; k < 4; ++k) {
        int idx = t * 4 + k;
        if (idx < NB) {
            int h = hist[idx];
            rlen_T[(size_t)idx * AB2 + blockIdx.x] = h;
            hist[idx] = run;
            cursor[idx] = run;
            run += h;
        }
    }
    __syncthreads();
    {
        int* lp = lscan + (size_t)blockIdx.x * LSTRIDE;
        for (int i = t; i < NB; i += 256) lp[i] = hist[i];
        if (t == 0) lp[NB] = nb;
    }
#pragma unroll
    for (int k = 0; k < 16; ++k) {
        if (dg[k] >= 0) {
            int pos = atomicAdd(&cursor[dg[k]], 1);
            stage[pos] = make_int2(pk[k], vb[k]);
        }
    }
    __syncthreads();
    for (int j = t; j < nb; j += 256) recs_tmp[(size_t)base + j] = stage[j];
}

// Half-bucket totals: btot[h*NB+k] = sum over half-h sort blocks of rlen_T[k][b].
__global__ __launch_bounds__(256) void row_sum(const int* __restrict__ rlen_T,
                                               int* __restrict__ btot) {
    __shared__ int ls[256];
    const int t = threadIdx.x;
    const int blk = blockIdx.x;
    const int h = (blk >= NB) ? 1 : 0;
    const int k = blk - h * NB;
    const int* rp = rlen_T + (size_t)k * AB2 + h * HABLK;
    int s = 0;
    for (int b = t; b < HABLK; b += 256) s += rp[b];
    ls[t] = s;
    __syncthreads();
    for (int off = 128; off; off >>= 1) {
        if (t < off) ls[t] += ls[t + off];
        __syncthreads();
    }
    if (t == 0) btot[blk] = ls[0];
}

// Exclusive scan of half-bucket totals (n up to 2048) -> bb[0..n], bb[n]=total.
__global__ __launch_bounds__(256) void scan_btot(
    const int* __restrict__ btot, int* __restrict__ bb, int n, int total) {
    __shared__ int ls[256];
    const int t = threadIdx.x;
    int a[8];
    const int idx = t * 8;
    int tsum = 0;
#pragma unroll
    for (int u = 0; u < 8; ++u) {
        a[u] = (idx + u < n) ? btot[idx + u] : 0;
        tsum += a[u];
    }
    ls[t] = tsum;
    __syncthreads();
    for (int off = 1; off < 256; off <<= 1) {
        int v = (t >= off) ? ls[t - off] : 0;
        __syncthreads();
        ls[t] += v;
        __syncthreads();
    }
    int excl = ls[t] - tsum;
#pragma unroll
    for (int u = 0; u < 8; ++u) {
        if (idx + u < n) bb[idx + u] = excl;
        excl += a[u];
    }
    if (t == 0) bb[n] = total;
}

// ---------------- collect + final counting sort per half-bucket ----------------

template <int DSHIFT, int NDEST>
__global__ __launch_bounds__(256) void collect_sort(
    const int2* __restrict__ recs_tmp, const int* __restrict__ lscan,
    const int* __restrict__ rlen_T, const int* __restrict__ bb,
    int2* __restrict__ recs_out, int* __restrict__ offs0, int* __restrict__ offs1,
    float* __restrict__ wsum0, float* __restrict__ wsum1, int nrows) {
    __shared__ int2 stage[CAPH];
    __shared__ int rloff[256];
    __shared__ int hist[NDEST];
    __shared__ int cursor[NDEST];
    __shared__ int sc[NDEST];
    __shared__ float wsumL[NDEST];
    __shared__ int nb_s;
    const int t = threadIdx.x;
    const int blk = blockIdx.x;
    const int h = (blk >= NB) ? 1 : 0;
    const int k = blk - h * NB;
    const int bsb = h * HABLK;
    int* __restrict__ offsH = h ? offs1 : offs0;
    float* __restrict__ wsumH = (wsum0 == nullptr) ? nullptr : (h ? wsum1 : wsum0);
    const int c0 = t * 2, c1 = t * 2 + 1;
    int s0 = 0, l0 = 0, s1 = 0, l1 = 0;
    if (c0 < HABLK) { s0 = lscan[(size_t)(bsb + c0) * LSTRIDE + k]; l0 = rlen_T[(size_t)k * AB2 + bsb + c0]; }
    if (c1 < HABLK) { s1 = lscan[(size_t)(bsb + c1) * LSTRIDE + k]; l1 = rlen_T[(size_t)k * AB2 + bsb + c1]; }
    int tsum = l0 + l1;
    rloff[t] = tsum;
    __syncthreads();
    for (int off = 1; off < 256; off <<= 1) {
        int v = (t >= off) ? rloff[t - off] : 0;
        __syncthreads();
        rloff[t] += v;
        __syncthreads();
    }
    if (t == 255) nb_s = rloff[255];
    int o0 = rloff[t] - tsum;
    int o1 = o0 + l0;
    for (int i = t; i < NDEST; i += 256) { hist[i] = 0; wsumL[i] = 0.0f; }
    __syncthreads();
    const int nb = min(nb_s, CAPH);
    {
        const int2* rp = recs_tmp + (size_t)(bsb + c0) * EPB + s0;
        for (int j = 0; j < l0; ++j) if (o0 + j < CAPH) stage[o0 + j] = rp[j];
        rp = recs_tmp + (size_t)(bsb + c1) * EPB + s1;
        for (int j = 0; j < l1; ++j) if (o1 + j < CAPH) stage[o1 + j] = rp[j];
    }
    __syncthreads();
    for (int j = t; j < nb; j += 256) {
        int2 r = stage[j];
        atomicAdd(&hist[r.x >> 20], 1);
        if (wsumH) atomicAdd(&wsumL[r.x >> 20], __int_as_float(r.y));
    }
    __syncthreads();
    if (t < NDEST) sc[t] = hist[t];
    __syncthreads();
    for (int off = 1; off < NDEST; off <<= 1) {
        int v = (t >= off && t < NDEST) ? sc[t - off] : 0;
        __syncthreads();
        if (t < NDEST) sc[t] += v;
        __syncthreads();
    }
    if (t < NDEST) {
        int excl = sc[t] - hist[t];
        cursor[t] = excl;
        int gd = (k << DSHIFT) + t;
        if (gd <= nrows) offsH[gd] = bb[blk] + excl;
        if (wsumH && gd < nrows) wsumH[gd] = wsumL[t];
    }
    __syncthreads();
    const int base_out = bb[blk];
    for (int j = t; j < nb; j += 256) {
        int2 r = stage[j];
        int pos = atomicAdd(&cursor[r.x >> 20], 1);
        recs_out[(size_t)base_out + pos] = make_int2(r.x & 0xFFFFF, r.y);
    }
}

// ---------------- segment sum: 16 lanes/row, half2 loads, unroll-8, 2 ranges ----------------

__global__ __launch_bounds__(256) void seg_gather16(
    const int* __restrict__ offs0, const int* __restrict__ offs1,
    const int2* __restrict__ recs,
    const __half* __restrict__ src16, float* __restrict__ dst, int nrows) {
    const int g = threadIdx.x >> 4, f2 = threadIdx.x & 15;
    const int row = blockIdx.x * 16 + g;
    if (row >= nrows) return;
    const __half2* __restrict__ s2 = (const __half2*)src16;
    float ax[8], ay[8];
#pragma unroll
    for (int u = 0; u < 8; ++u) { ax[u] = 0.0f; ay[u] = 0.0f; }
    for (int h = 0; h < 2; ++h) {
        const int* __restrict__ of = h ? offs1 : offs0;
        int j = of[row];
        const int j1 = of[row + 1];
        for (; j + 8 <= j1; j += 8) {
            int2 r[8];
#pragma unroll
            for (int u = 0; u < 8; ++u) r[u] = recs[j + u];
            __half2 hh[8];
#pragma unroll
            for (int u = 0; u < 8; ++u) hh[u] = s2[(size_t)r[u].x * 16 + f2];
#pragma unroll
            for (int u = 0; u < 8; ++u) {
                float w = __int_as_float(r[u].y);
                float2 f = __half22float2(hh[u]);
                ax[u] = fmaf(f.x, w, ax[u]);
                ay[u] = fmaf(f.y, w, ay[u]);
            }
        }
        for (; j < j1; ++j) {
            int2 ra = recs[j];
            __half2 ha = s2[(size_t)ra.x * 16 + f2];
            float wa = __int_as_float(ra.y);
            float2 fa = __half22float2(ha);
            ax[0] = fmaf(fa.x, wa, ax[0]);
            ay[0] = fmaf(fa.y, wa, ay[0]);
        }
    }
    float2 r;
    r.x = ((ax[0] + ax[1]) + (ax[2] + ax[3])) + ((ax[4] + ax[5]) + (ax[6] + ax[7]));
    r.y = ((ay[0] + ay[1]) + (ay[2] + ay[3])) + ((ay[4] + ay[5]) + (ay[6] + ay[7]));
    ((float2*)dst)[(size_t)row * 16 + f2] = r;
}

// ---------------- fallback atomic scatter (used only if ws too small) ----------------

__global__ __launch_bounds__(256) void scatter_edges(
    const int* __restrict__ src_idx, const int* __restrict__ dst_idx,
    const float* __restrict__ ev, const float* __restrict__ src,
    float* __restrict__ dst, int n_edges) {
    int e = blockIdx.x * 8 + (threadIdx.x >> 5);
    int f = threadIdx.x & 31;
    if (e >= n_edges) return;
    atomicAdd(&dst[(size_t)dst_idx[e] * FM + f], src[(size_t)src_idx[e] * FM + f] * ev[e]);
}

// ---------------- MLP + LayerNorm kernels ----------------

__global__ __launch_bounds__(256) void pc_mlp(
    const float* __restrict__ cond,
    const float* __restrict__ W1, const float* __restrict__ b1,
    const float* __restrict__ W2, const float* __restrict__ b2,
    float* __restrict__ dst, float* __restrict__ dst2, int nrows) {
    __shared__ float sW2[64 * FM];
    __shared__ float sh[4][64];
    for (int i = threadIdx.x; i < 64 * FM; i += 256) sW2[i] = W2[i];
    int g = threadIdx.x >> 6, l = threadIdx.x & 63, l32 = l & 31, half = l >> 5;
    float w1l = W1[l], b1l = b1[l], b2l = b2[l32];
    __syncthreads();
    for (int row = blockIdx.x * 4 + g; row < nrows; row += gridDim.x * 4) {
        float c = cond[row];
        sh[g][l] = fmaxf(fmaf(c, w1l, b1l), 0.0f);
        float y0 = 0.0f, y1 = 0.0f;
#pragma unroll
        for (int k = 0; k < 32; k += 8) {
            float4 h0 = *(const float4*)&sh[g][half * 32 + k];
            float4 h1 = *(const float4*)&sh[g][half * 32 + k + 4];
            y0 = fmaf(h0.x, sW2[(half * 32 + k + 0) * FM + l32], y0);
            y0 = fmaf(h0.y, sW2[(half * 32 + k + 1) * FM + l32], y0);
            y0 = fmaf(h0.z, sW2[(half * 32 + k + 2) * FM + l32], y0);
            y0 = fmaf(h0.w, sW2[(half * 32 + k + 3) * FM + l32], y0);
            y1 = fmaf(h1.x, sW2[(half * 32 + k + 4) * FM + l32], y1);
            y1 = fmaf(h1.y, sW2[(half * 32 + k + 5) * FM + l32], y1);
            y1 = fmaf(h1.z, sW2[(half * 32 + k + 6) * FM + l32], y1);
            y1 = fmaf(h1.w, sW2[(half * 32 + k + 7) * FM + l32], y1);
        }
        float y = y0 + y1;
        y += __shfl_xor(y, 32);
        y += b2l;
        float s = warp_sum32(y);
        float mu = s * (1.0f / 32.0f);
        float d = y - mu;
        float v = warp_sum32(d * d);
        if (half == 0) {
            float o = d * rsqrtf(v * (1.0f / 32.0f) + LN_EPS);
            dst[(size_t)row * FM + l32] = o;
            dst2[(size_t)row * FM + l32] = o;
        }
    }
}

// IN = NSEG*32 -> 64 (relu) -> 32, LN. Layer-1 weights in registers, 4-way
// ILP-split accumulation. If ws0 != nullptr (NSEG==3), third segment is
// broadcast scalar ws0[row]+ws1[row].
template <int NSEG>
__global__ __launch_bounds__(256) void mlp_ln(
    const float* __restrict__ s0, const float* __restrict__ s1,
    const float* __restrict__ s2,
    const float* __restrict__ ws0, const float* __restrict__ ws1,
    const float* __restrict__ W1, const float* __restrict__ b1,
    const float* __restrict__ W2, const float* __restrict__ b2,
    float* __restrict__ dst, __half* __restrict__ dst16, int nrows) {
    constexpr int IN = NSEG * FM;
    __shared__ float sW2[64 * FM];
    __shared__ float sx[4][IN];
    __shared__ float sh[4][64];
    for (int i = threadIdx.x; i < 64 * FM; i += 256) sW2[i] = W2[i];
    int g = threadIdx.x >> 6, l = threadIdx.x & 63, l32 = l & 31, half = l >> 5;
    float w1r[IN];
#pragma unroll
    for (int k = 0; k < IN; ++k) w1r[k] = W1[k * 64 + l];
    float b1l = b1[l], b2l = b2[l32];
    __syncthreads();
    for (int row = blockIdx.x * 4 + g; row < nrows; row += gridDim.x * 4) {
#pragma unroll
        for (int i = l; i < IN; i += 64) {
            float v;
            if (NSEG >= 3 && i >= 64)
                v = ws0 ? (ws0[row] + ws1[row]) : s2[(size_t)row * FM + (i & 31)];
            else
                v = (i < 32 ? s0 : s1)[(size_t)row * FM + (i & 31)];
            sx[g][i] = v;
        }
        float a0 = 0.0f, a1 = 0.0f, a2 = 0.0f, a3 = 0.0f;
#pragma unroll
        for (int k = 0; k < IN; k += 16) {
            float4 x0 = *(const float4*)&sx[g][k + 0];
            float4 x1 = *(const float4*)&sx[g][k + 4];
            float4 x2 = *(const float4*)&sx[g][k + 8];
            float4 x3 = *(const float4*)&sx[g][k + 12];
            a0 = fmaf(x0.x, w1r[k + 0], a0);
            a0 = fmaf(x0.y, w1r[k + 1], a0);
            a0 = fmaf(x0.z, w1r[k + 2], a0);
            a0 = fmaf(x0.w, w1r[k + 3], a0);
            a1 = fmaf(x1.x, w1r[k + 4], a1);
            a1 = fmaf(x1.y, w1r[k + 5], a1);
            a1 = fmaf(x1.z, w1r[k + 6], a1);
            a1 = fmaf(x1.w, w1r[k + 7], a1);
            a2 = fmaf(x2.x, w1r[k + 8], a2);
            a2 = fmaf(x2.y, w1r[k + 9], a2);
            a2 = fmaf(x2.z, w1r[k + 10], a2);
            a2 = fmaf(x2.w, w1r[k + 11], a2);
            a3 = fmaf(x3.x, w1r[k + 12], a3);
            a3 = fmaf(x3.y, w1r[k + 13], a3);
            a3 = fmaf(x3.z, w1r[k + 14], a3);
            a3 = fmaf(x3.w, w1r[k + 15], a3);
        }
        float acc = ((a0 + a1) + (a2 + a3)) + b1l;
        sh[g][l] = fmaxf(acc, 0.0f);
        float y0 = 0.0f, y1 = 0.0f;
#pragma unroll
        for (int k = 0; k < 32; k += 8) {
            float4 h0 = *(const float4*)&sh[g][half * 32 + k];
            float4 h1 = *(const float4*)&sh[g][half * 32 + k + 4];
            y0 = fmaf(h0.x, sW2[(half * 32 + k + 0) * FM + l32], y0);
            y0 = fmaf(h0.y, sW2[(half * 32 + k + 1) * FM + l32], y0);
            y0 = fmaf(h0.z, sW2[(half * 32 + k + 2) * FM + l32], y0);
            y0 = fmaf(h0.w, sW2[(half * 32 + k + 3) * FM + l32], y0);
            y1 = fmaf(h1.x, sW2[(half * 32 + k + 4) * FM + l32], y1);
            y1 = fmaf(h1.y, sW2[(half * 32 + k + 5) * FM + l32], y1);
            y1 = fmaf(h1.z, sW2[(half * 32 + k + 6) * FM + l32], y1);
            y1 = fmaf(h1.w, sW2[(half * 32 + k + 7) * FM + l32], y1);
        }
        float y = y0 + y1;
        y += __shfl_xor(y, 32);
        y += b2l;
        float s = warp_sum32(y);
        float mu = s * (1.0f / 32.0f);
        float d = y - mu;
        float v = warp_sum32(d * d);
        if (half == 0) {
            float o = d * rsqrtf(v * (1.0f / 32.0f) + LN_EPS);
            dst[(size_t)row * FM + l32] = o;
            if (dst16) dst16[(size_t)row * FM + l32] = __float2half(o);
        }
    }
}

__global__ __launch_bounds__(256) void out_mlp(
    const float* __restrict__ x,
    const float* __restrict__ W1, const float* __restrict__ b1,
    const float* __restrict__ W2, const float* __restrict__ b2,
    float* __restrict__ dst, int nrows) {
    __shared__ float sW2[64 * 16];
    __shared__ float sx[4][FM];
    __shared__ float sh[4][64];
    for (int i = threadIdx.x; i < 64 * 16; i += 256) sW2[i] = W2[i];
    int g = threadIdx.x >> 6, l = threadIdx.x & 63;
    int o = l & 15, q = l >> 4;
    float w1r[FM];
#pragma unroll
    for (int k = 0; k < FM; ++k) w1r[k] = W1[k * 64 + l];
    float b1l = b1[l];
    float b2o = b2[o];
    __syncthreads();
    for (int row = blockIdx.x * 4 + g; row < nrows; row += gridDim.x * 4) {
        if (l < FM) sx[g][l] = x[(size_t)row * FM + l];
        float a0 = 0.0f, a1 = 0.0f, a2 = 0.0f, a3 = 0.0f;
#pragma unroll
        for (int k = 0; k < FM; k += 16) {
            float4 x0 = *(const float4*)&sx[g][k + 0];
            float4 x1 = *(const float4*)&sx[g][k + 4];
            float4 x2 = *(const float4*)&sx[g][k + 8];
            float4 x3 = *(const float4*)&sx[g][k + 12];
            a0 = fmaf(x0.x, w1r[k + 0], a0);
            a0 = fmaf(x0.y, w1r[k + 1], a0);
            a0 = fmaf(x0.z, w1r[k + 2], a0);
            a0 = fmaf(x0.w, w1r[k + 3], a0);
            a1 = fmaf(x1.x, w1r[k + 4], a1);
            a1 = fmaf(x1.y, w1r[k + 5], a1);
            a1 = fmaf(x1.z, w1r[k + 6], a1);
            a1 = fmaf(x1.w, w1r[k + 7], a1);
            a2 = fmaf(x2.x, w1r[k + 8], a2);
            a2 = fmaf(x2.y, w1r[k + 9], a2);
            a2 = fmaf(x2.z, w1r[k + 10], a2);
            a2 = fmaf(x2.w, w1r[k + 11], a2);
            a3 = fmaf(x3.x, w1r[k + 12], a3);
            a3 = fmaf(x3.y, w1r[k + 13], a3);
            a3 = fmaf(x3.z, w1r[k + 14], a3);
            a3 = fmaf(x3.w, w1r[k + 15], a3);
        }
        float acc = ((a0 + a1) + (a2 + a3)) + b1l;
        sh[g][l] = fmaxf(acc, 0.0f);
        float y0 = 0.0f, y1 = 0.0f;
#pragma unroll
        for (int k = 0; k < 16; k += 8) {
            int kk = q * 16 + k;
            float4 h0 = *(const float4*)&sh[g][kk];
            float4 h1 = *(const float4*)&sh[g][kk + 4];
            y0 = fmaf(h0.x, sW2[(kk + 0) * 16 + o], y0);
            y0 = fmaf(h0.y, sW2[(kk + 1) * 16 + o], y0);
            y0 = fmaf(h0.z, sW2[(kk + 2) * 16 + o], y0);
            y0 = fmaf(h0.w, sW2[(kk + 3) * 16 + o], y0);
            y1 = fmaf(h1.x, sW2[(kk + 4) * 16 + o], y1);
            y1 = fmaf(h1.y, sW2[(kk + 5) * 16 + o], y1);
            y1 = fmaf(h1.z, sW2[(kk + 6) * 16 + o], y1);
            y1 = fmaf(h1.w, sW2[(kk + 7) * 16 + o], y1);
        }
        float y = y0 + y1;
        y += __shfl_xor(y, 16);
        y += __shfl_xor(y, 32);
        if (q == 0) dst[(size_t)row * 16 + o] = 1.0f / (1.0f + expf(-(y + b2o)));
    }
}

// ---------------- launcher ----------------

extern "C" void kernel_launch(void* const* d_in, const int* in_sizes, int n_in,
                              void* d_out, int out_size, void* d_ws, size_t ws_size,
                              hipStream_t stream) {
    const int*   edge_var   = (const int*)d_in[0];
    const int*   edge_const = (const int*)d_in[1];
    const float* edge_val   = (const float*)d_in[2];
    const float* cond       = (const float*)d_in[3];
    const float* pc_W1 = (const float*)d_in[6];
    const float* pc_b1 = (const float*)d_in[7];
    const float* pc_W2 = (const float*)d_in[8];
    const float* pc_b2 = (const float*)d_in[9];
    const float* cu_W1 = (const float*)d_in[10];
    const float* cu_b1 = (const float*)d_in[11];
    const float* cu_W2 = (const float*)d_in[12];
    const float* cu_b2 = (const float*)d_in[13];
    const float* vu_W1 = (const float*)d_in[14];
    const float* vu_b1 = (const float*)d_in[15];
    const float* vu_W2 = (const float*)d_in[16];
    const float* vu_b2 = (const float*)d_in[17];
    const float* out_W1 = (const float*)d_in[18];
    const float* out_b1 = (const float*)d_in[19];
    const float* out_W2 = (const float*)d_in[20];
    const float* out_b2 = (const float*)d_in[21];

    float* ws = (float*)d_ws;
    size_t off = 0;
    auto alloc = [&](size_t nelems) {
        float* p = ws + off;
        off += (nelems + 15) & ~(size_t)15;
        return p;
    };
    float*  emb     = alloc(CONST_COUNT * FM);
    float*  cons    = alloc(CONST_COUNT * FM);
    float*  vars    = alloc(VAR_COUNT * FM);
    float*  msg     = alloc(VAR_COUNT * FM);
    __half* vars16  = (__half*)alloc(VAR_COUNT * FM / 2);
    __half* cons16  = (__half*)alloc(CONST_COUNT * FM / 2);
    int2*   recs_t  = (int2*)alloc((size_t)N_EDGES * 2);
    int2*   recs_c  = (int2*)alloc((size_t)N_EDGES * 2);
    int2*   recs_v  = (int2*)alloc((size_t)N_EDGES * 2);
    int*    lscan   = (int*)alloc((size_t)ABLK * LSTRIDE);
    int*    rlen_T  = (int*)alloc((size_t)NB * AB2);
    int*    btot    = (int*)alloc(2 * NB);
    int*    bb_c    = (int*)alloc(2 * NB + 1);
    int*    bb_v    = (int*)alloc(2 * NB + 1);
    int*    offs_c0 = (int*)alloc(CONST_COUNT + 1);
    int*    offs_c1 = (int*)alloc(CONST_COUNT + 1);
    int*    offs_v0 = (int*)alloc(VAR_COUNT + 1);
    int*    offs_v1 = (int*)alloc(VAR_COUNT + 1);
    float*  wsum_c0 = alloc(CONST_COUNT);
    float*  wsum_c1 = alloc(CONST_COUNT);
    size_t need_bytes = off * sizeof(float);
    bool fast = ws_size >= need_bytes;

    if (fast) {
        // const-direction: dest = edge_const (64 dests/bucket)
        bucket_sort<6><<<ABLK, 256, 0, stream>>>(edge_const, edge_var, edge_val,
                                                 recs_t, lscan, rlen_T, N_EDGES);
        row_sum<<<2 * NB, 256, 0, stream>>>(rlen_T, btot);
        scan_btot<<<1, 256, 0, stream>>>(btot, bb_c, 2 * NB, N_EDGES);
        collect_sort<6, 64><<<2 * NB, 256, 0, stream>>>(
            recs_t, lscan, rlen_T, bb_c, recs_c, offs_c0, offs_c1,
            wsum_c0, wsum_c1, CONST_COUNT);
        // var-direction: dest = edge_var (128 dests/bucket)
        bucket_sort<7><<<ABLK, 256, 0, stream>>>(edge_var, edge_const, edge_val,
                                                 recs_t, lscan, rlen_T, N_EDGES);
        row_sum<<<2 * NB, 256, 0, stream>>>(rlen_T, btot);
        scan_btot<<<1, 256, 0, stream>>>(btot, bb_v, 2 * NB, N_EDGES);
        collect_sort<7, 128><<<2 * NB, 256, 0, stream>>>(
            recs_t, lscan, rlen_T, bb_v, recs_v, offs_v0, offs_v1,
            nullptr, nullptr, VAR_COUNT);
    }

    init_vars<<<(VAR_COUNT * FM + 255) / 256, 256, 0, stream>>>(vars, VAR_COUNT * FM);
    pc_mlp<<<2048, 256, 0, stream>>>(cond, pc_W1, pc_b1, pc_W2, pc_b2, emb, cons,
                                     CONST_COUNT);

    for (int pass = 0; pass < 3; ++pass) {
        if (fast) {
            if (pass == 0) {
                // v2c pass 0: variables == ones -> broadcast wsum (no gather)
                mlp_ln<3><<<2048, 256, 0, stream>>>(cons, emb, nullptr, wsum_c0, wsum_c1,
                                                    cu_W1, cu_b1, cu_W2, cu_b2,
                                                    cons, cons16, CONST_COUNT);
            } else {
                seg_gather16<<<(CONST_COUNT + 15) / 16, 256, 0, stream>>>(
                    offs_c0, offs_c1, recs_c, vars16, msg, CONST_COUNT);
                mlp_ln<3><<<2048, 256, 0, stream>>>(cons, emb, msg, nullptr, nullptr,
                                                    cu_W1, cu_b1, cu_W2, cu_b2,
                                                    cons, cons16, CONST_COUNT);
            }
            seg_gather16<<<(VAR_COUNT + 15) / 16, 256, 0, stream>>>(
                offs_v0, offs_v1, recs_v, cons16, msg, VAR_COUNT);
            mlp_ln<2><<<2048, 256, 0, stream>>>(vars, msg, nullptr, nullptr, nullptr,
                                                vu_W1, vu_b1, vu_W2, vu_b2,
                                                vars, (pass < 2) ? vars16 : nullptr,
                                                VAR_COUNT);
        } else {
            hipMemsetAsync(msg, 0, (size_t)CONST_COUNT * FM * sizeof(float), stream);
            scatter_edges<<<N_EDGES / 8, 256, 0, stream>>>(edge_var, edge_const, edge_val,
                                                           vars, msg, N_EDGES);
            mlp_ln<3><<<2048, 256, 0, stream>>>(cons, emb, msg, nullptr, nullptr,
                                                cu_W1, cu_b1, cu_W2, cu_b2,
                                                cons, nullptr, CONST_COUNT);
            hipMemsetAsync(msg, 0, (size_t)VAR_COUNT * FM * sizeof(float), stream);
            scatter_edges<<<N_EDGES / 8, 256, 0, stream>>>(edge_const, edge_var, edge_val,
                                                           cons, msg, N_EDGES);
            mlp_ln<2><<<2048, 256, 0, stream>>>(vars, msg, nullptr, nullptr, nullptr,
                                                vu_W1, vu_b1, vu_W2, vu_b2,
                                                vars, nullptr, VAR_COUNT);
        }
    }

    out_mlp<<<2048, 256, 0, stream>>>(vars, out_W1, out_b1, out_W2, out_b2,
                                      (float*)d_out, VAR_COUNT);
}

// Round 12
// 724.618 us; speedup vs baseline: 1.0428x; 1.0428x over previous
//
#include <hip/hip_runtime.h>
#include <hip/hip_fp16.h>
#include <math.h>

#define FM 32
#define N_EDGES 3200000
#define VAR_COUNT 100000
#define CONST_COUNT 50000
#define LN_EPS 1e-5f

#define EPB 4096                 // edges per sort block
#define ABLK 782                 // ceil(N_EDGES / EPB)
#define HABLK 391                // sort blocks per half
#define NB 782                   // buckets (64 consts or 128 vars each)
#define AB2 784                  // padded stride for transposed rlen matrix
#define LSTRIDE 784              // NB + 2
#define CAPH 2560                // max records per half-bucket in LDS (+11 sigma)

static __device__ __forceinline__ float warp_sum32(float v) {
#pragma unroll
    for (int m = 16; m; m >>= 1) v += __shfl_xor(v, m);
    return v;
}

__global__ void init_vars(float* __restrict__ v, int n) {
    int i = blockIdx.x * 256 + threadIdx.x;
    if (i < n) v[i] = 1.0f;
}

// ---------------- block-local bucket sort (no global atomics) ----------------

template <int DSHIFT>
__global__ __launch_bounds__(256) void bucket_sort(
    const int* __restrict__ dest_arr, const int* __restrict__ src_arr,
    const float* __restrict__ val_arr,
    int2* __restrict__ recs_tmp, int* __restrict__ lscan, int* __restrict__ rlen_T,
    int n) {
    __shared__ int hist[NB];
    __shared__ int cursor[NB];
    __shared__ int chunk[256];
    __shared__ int2 stage[EPB];
    const int t = threadIdx.x;
    const int base = blockIdx.x * EPB;
    const int nb = min(EPB, n - base);
    for (int i = t; i < NB; i += 256) hist[i] = 0;
    __syncthreads();
    int dg[16], pk[16], vb[16];
#pragma unroll
    for (int k = 0; k < 16; ++k) {
        int j = k * 256 + t;
        dg[k] = -1;
        if (j < nb) {
            int dest = dest_arr[base + j];
            int src  = src_arr[base + j];
            vb[k] = __float_as_int(val_arr[base + j]);
            dg[k] = dest >> DSHIFT;
            pk[k] = ((dest & ((1 << DSHIFT) - 1)) << 20) | src;
            atomicAdd(&hist[dg[k]], 1);
        }
    }
    __syncthreads();
    int sum = 0;
#pragma unroll
    for (int k = 0; k < 4; ++k) {
        int idx = t * 4 + k;
        if (idx < NB) sum += hist[idx];
    }
    chunk[t] = sum;
    __syncthreads();
    for (int off = 1; off < 256; off <<= 1) {
        int v = (t >= off) ? chunk[t - off] : 0;
        __syncthreads();
        chunk[t] += v;
        __syncthreads();
    }
    int run = chunk[t] - sum;
#pragma unroll
    for (int k = 0; k < 4; ++k) {
        int idx = t * 4 + k;
        if (idx < NB) {
            int h = hist[idx];
            rlen_T[(size_t)idx * AB2 + blockIdx.x] = h;
            hist[idx] = run;
            cursor[idx] = run;
            run += h;
        }
    }
    __syncthreads();
    {
        int* lp = lscan + (size_t)blockIdx.x * LSTRIDE;
        for (int i = t; i < NB; i += 256) lp[i] = hist[i];
        if (t == 0) lp[NB] = nb;
    }
#pragma unroll
    for (int k = 0; k < 16; ++k) {
        if (dg[k] >= 0) {
            int pos = atomicAdd(&cursor[dg[k]], 1);
            stage[pos] = make_int2(pk[k], vb[k]);
        }
    }
    __syncthreads();
    for (int j = t; j < nb; j += 256) recs_tmp[(size_t)base + j] = stage[j];
}

// Half-bucket totals: btot[h*NB+k] = sum over half-h sort blocks of rlen_T[k][b].
__global__ __launch_bounds__(256) void row_sum(const int* __restrict__ rlen_T,
                                               int* __restrict__ btot) {
    __shared__ int ls[256];
    const int t = threadIdx.x;
    const int blk = blockIdx.x;
    const int h = (blk >= NB) ? 1 : 0;
    const int k = blk - h * NB;
    const int* rp = rlen_T + (size_t)k * AB2 + h * HABLK;
    int s = 0;
    for (int b = t; b < HABLK; b += 256) s += rp[b];
    ls[t] = s;
    __syncthreads();
    for (int off = 128; off; off >>= 1) {
        if (t < off) ls[t] += ls[t + off];
        __syncthreads();
    }
    if (t == 0) btot[blk] = ls[0];
}

// Exclusive scan of half-bucket totals (n up to 2048) -> bb[0..n], bb[n]=total.
__global__ __launch_bounds__(256) void scan_btot(
    const int* __restrict__ btot, int* __restrict__ bb, int n, int total) {
    __shared__ int ls[256];
    const int t = threadIdx.x;
    int a[8];
    const int idx = t * 8;
    int tsum = 0;
#pragma unroll
    for (int u = 0; u < 8; ++u) {
        a[u] = (idx + u < n) ? btot[idx + u] : 0;
        tsum += a[u];
    }
    ls[t] = tsum;
    __syncthreads();
    for (int off = 1; off < 256; off <<= 1) {
        int v = (t >= off) ? ls[t - off] : 0;
        __syncthreads();
        ls[t] += v;
        __syncthreads();
    }
    int excl = ls[t] - tsum;
#pragma unroll
    for (int u = 0; u < 8; ++u) {
        if (idx + u < n) bb[idx + u] = excl;
        excl += a[u];
    }
    if (t == 0) bb[n] = total;
}

// ---------------- collect + final counting sort per half-bucket ----------------

template <int DSHIFT, int NDEST>
__global__ __launch_bounds__(256) void collect_sort(
    const int2* __restrict__ recs_tmp, const int* __restrict__ lscan,
    const int* __restrict__ rlen_T, const int* __restrict__ bb,
    int2* __restrict__ recs_out, int* __restrict__ offs0, int* __restrict__ offs1,
    float* __restrict__ wsum0, float* __restrict__ wsum1, int nrows) {
    __shared__ int2 stage[CAPH];
    __shared__ int rloff[256];
    __shared__ int hist[NDEST];
    __shared__ int cursor[NDEST];
    __shared__ int sc[NDEST];
    __shared__ float wsumL[NDEST];
    __shared__ int nb_s;
    const int t = threadIdx.x;
    const int blk = blockIdx.x;
    const int h = (blk >= NB) ? 1 : 0;
    const int k = blk - h * NB;
    const int bsb = h * HABLK;
    int* __restrict__ offsH = h ? offs1 : offs0;
    float* __restrict__ wsumH = (wsum0 == nullptr) ? nullptr : (h ? wsum1 : wsum0);
    const int c0 = t * 2, c1 = t * 2 + 1;
    int s0 = 0, l0 = 0, s1 = 0, l1 = 0;
    if (c0 < HABLK) { s0 = lscan[(size_t)(bsb + c0) * LSTRIDE + k]; l0 = rlen_T[(size_t)k * AB2 + bsb + c0]; }
    if (c1 < HABLK) { s1 = lscan[(size_t)(bsb + c1) * LSTRIDE + k]; l1 = rlen_T[(size_t)k * AB2 + bsb + c1]; }
    int tsum = l0 + l1;
    rloff[t] = tsum;
    __syncthreads();
    for (int off = 1; off < 256; off <<= 1) {
        int v = (t >= off) ? rloff[t - off] : 0;
        __syncthreads();
        rloff[t] += v;
        __syncthreads();
    }
    if (t == 255) nb_s = rloff[255];
    int o0 = rloff[t] - tsum;
    int o1 = o0 + l0;
    for (int i = t; i < NDEST; i += 256) { hist[i] = 0; wsumL[i] = 0.0f; }
    __syncthreads();
    const int nb = min(nb_s, CAPH);
    {
        const int2* rp = recs_tmp + (size_t)(bsb + c0) * EPB + s0;
        for (int j = 0; j < l0; ++j) if (o0 + j < CAPH) stage[o0 + j] = rp[j];
        rp = recs_tmp + (size_t)(bsb + c1) * EPB + s1;
        for (int j = 0; j < l1; ++j) if (o1 + j < CAPH) stage[o1 + j] = rp[j];
    }
    __syncthreads();
    for (int j = t; j < nb; j += 256) {
        int2 r = stage[j];
        atomicAdd(&hist[r.x >> 20], 1);
        if (wsumH) atomicAdd(&wsumL[r.x >> 20], __int_as_float(r.y));
    }
    __syncthreads();
    if (t < NDEST) sc[t] = hist[t];
    __syncthreads();
    for (int off = 1; off < NDEST; off <<= 1) {
        int v = (t >= off && t < NDEST) ? sc[t - off] : 0;
        __syncthreads();
        if (t < NDEST) sc[t] += v;
        __syncthreads();
    }
    if (t < NDEST) {
        int excl = sc[t] - hist[t];
        cursor[t] = excl;
        int gd = (k << DSHIFT) + t;
        if (gd <= nrows) offsH[gd] = bb[blk] + excl;
        if (wsumH && gd < nrows) wsumH[gd] = wsumL[t];
    }
    __syncthreads();
    const int base_out = bb[blk];
    for (int j = t; j < nb; j += 256) {
        int2 r = stage[j];
        int pos = atomicAdd(&cursor[r.x >> 20], 1);
        recs_out[(size_t)base_out + pos] = make_int2(r.x & 0xFFFFF, r.y);
    }
}

// ---------------- segment sum: 16 lanes/row, half2 loads, unroll-8, 2 ranges ----------------

__global__ __launch_bounds__(256) void seg_gather16(
    const int* __restrict__ offs0, const int* __restrict__ offs1,
    const int2* __restrict__ recs,
    const __half* __restrict__ src16, float* __restrict__ dst, int nrows) {
    const int g = threadIdx.x >> 4, f2 = threadIdx.x & 15;
    const int row = blockIdx.x * 16 + g;
    if (row >= nrows) return;
    const __half2* __restrict__ s2 = (const __half2*)src16;
    float ax[8], ay[8];
#pragma unroll
    for (int u = 0; u < 8; ++u) { ax[u] = 0.0f; ay[u] = 0.0f; }
    for (int h = 0; h < 2; ++h) {
        const int* __restrict__ of = h ? offs1 : offs0;
        int j = of[row];
        const int j1 = of[row + 1];
        for (; j + 8 <= j1; j += 8) {
            int2 r[8];
#pragma unroll
            for (int u = 0; u < 8; ++u) r[u] = recs[j + u];
            __half2 hh[8];
#pragma unroll
            for (int u = 0; u < 8; ++u) hh[u] = s2[(size_t)r[u].x * 16 + f2];
#pragma unroll
            for (int u = 0; u < 8; ++u) {
                float w = __int_as_float(r[u].y);
                float2 f = __half22float2(hh[u]);
                ax[u] = fmaf(f.x, w, ax[u]);
                ay[u] = fmaf(f.y, w, ay[u]);
            }
        }
        for (; j < j1; ++j) {
            int2 ra = recs[j];
            __half2 ha = s2[(size_t)ra.x * 16 + f2];
            float wa = __int_as_float(ra.y);
            float2 fa = __half22float2(ha);
            ax[0] = fmaf(fa.x, wa, ax[0]);
            ay[0] = fmaf(fa.y, wa, ay[0]);
        }
    }
    float2 r;
    r.x = ((ax[0] + ax[1]) + (ax[2] + ax[3])) + ((ax[4] + ax[5]) + (ax[6] + ax[7]));
    r.y = ((ay[0] + ay[1]) + (ay[2] + ay[3])) + ((ay[4] + ay[5]) + (ay[6] + ay[7]));
    ((float2*)dst)[(size_t)row * 16 + f2] = r;
}

// ---------------- fallback atomic scatter (used only if ws too small) ----------------

__global__ __launch_bounds__(256) void scatter_edges(
    const int* __restrict__ src_idx, const int* __restrict__ dst_idx,
    const float* __restrict__ ev, const float* __restrict__ src,
    float* __restrict__ dst, int n_edges) {
    int e = blockIdx.x * 8 + (threadIdx.x >> 5);
    int f = threadIdx.x & 31;
    if (e >= n_edges) return;
    atomicAdd(&dst[(size_t)dst_idx[e] * FM + f], src[(size_t)src_idx[e] * FM + f] * ev[e]);
}

// ---------------- MLP + LayerNorm kernels (software-pipelined row loops) ----------------

__global__ __launch_bounds__(256) void pc_mlp(
    const float* __restrict__ cond,
    const float* __restrict__ W1, const float* __restrict__ b1,
    const float* __restrict__ W2, const float* __restrict__ b2,
    float* __restrict__ dst, float* __restrict__ dst2, int nrows) {
    __shared__ float sW2[64 * FM];
    __shared__ float sh[4][64];
    for (int i = threadIdx.x; i < 64 * FM; i += 256) sW2[i] = W2[i];
    int g = threadIdx.x >> 6, l = threadIdx.x & 63, l32 = l & 31, half = l >> 5;
    float w1l = W1[l], b1l = b1[l], b2l = b2[l32];
    __syncthreads();
    const int stride = gridDim.x * 4;
    int row = blockIdx.x * 4 + g;
    float ccur = (row < nrows) ? cond[row] : 0.0f;
    for (; row < nrows; row += stride) {
        int rn = row + stride;
        float cnxt = (rn < nrows) ? cond[rn] : 0.0f;
        sh[g][l] = fmaxf(fmaf(ccur, w1l, b1l), 0.0f);
        float y0 = 0.0f, y1 = 0.0f;
#pragma unroll
        for (int k = 0; k < 32; k += 8) {
            float4 h0 = *(const float4*)&sh[g][half * 32 + k];
            float4 h1 = *(const float4*)&sh[g][half * 32 + k + 4];
            y0 = fmaf(h0.x, sW2[(half * 32 + k + 0) * FM + l32], y0);
            y0 = fmaf(h0.y, sW2[(half * 32 + k + 1) * FM + l32], y0);
            y0 = fmaf(h0.z, sW2[(half * 32 + k + 2) * FM + l32], y0);
            y0 = fmaf(h0.w, sW2[(half * 32 + k + 3) * FM + l32], y0);
            y1 = fmaf(h1.x, sW2[(half * 32 + k + 4) * FM + l32], y1);
            y1 = fmaf(h1.y, sW2[(half * 32 + k + 5) * FM + l32], y1);
            y1 = fmaf(h1.z, sW2[(half * 32 + k + 6) * FM + l32], y1);
            y1 = fmaf(h1.w, sW2[(half * 32 + k + 7) * FM + l32], y1);
        }
        float y = y0 + y1;
        y += __shfl_xor(y, 32);
        y += b2l;
        float s = warp_sum32(y);
        float mu = s * (1.0f / 32.0f);
        float d = y - mu;
        float v = warp_sum32(d * d);
        if (half == 0) {
            float o = d * rsqrtf(v * (1.0f / 32.0f) + LN_EPS);
            dst[(size_t)row * FM + l32] = o;
            dst2[(size_t)row * FM + l32] = o;
        }
        ccur = cnxt;
    }
}

// IN = NSEG*32 -> 64 (relu) -> 32, LN. Layer-1 weights in registers; next
// row's inputs are prefetched into registers while the current row computes.
template <int NSEG>
__global__ __launch_bounds__(256) void mlp_ln(
    const float* __restrict__ s0, const float* __restrict__ s1,
    const float* __restrict__ s2,
    const float* __restrict__ ws0, const float* __restrict__ ws1,
    const float* __restrict__ W1, const float* __restrict__ b1,
    const float* __restrict__ W2, const float* __restrict__ b2,
    float* __restrict__ dst, __half* __restrict__ dst16, int nrows) {
    constexpr int IN = NSEG * FM;
    __shared__ float sW2[64 * FM];
    __shared__ float sx[4][IN];
    __shared__ float sh[4][64];
    for (int i = threadIdx.x; i < 64 * FM; i += 256) sW2[i] = W2[i];
    int g = threadIdx.x >> 6, l = threadIdx.x & 63, l32 = l & 31, half = l >> 5;
    float w1r[IN];
#pragma unroll
    for (int k = 0; k < IN; ++k) w1r[k] = W1[k * 64 + l];
    float b1l = b1[l], b2l = b2[l32];
    __syncthreads();
    const int stride = gridDim.x * 4;
    int row = blockIdx.x * 4 + g;
    float acur = 0.0f, bcur = 0.0f;
    if (row < nrows) {
        acur = (l < 32 ? s0 : s1)[(size_t)row * FM + l32];
        if (NSEG >= 3)
            bcur = ws0 ? (ws0[row] + ws1[row])
                       : ((l < 32) ? s2[(size_t)row * FM + l32] : 0.0f);
    }
    for (; row < nrows; row += stride) {
        int rn = row + stride;
        float anxt = 0.0f, bnxt = 0.0f;
        if (rn < nrows) {
            anxt = (l < 32 ? s0 : s1)[(size_t)rn * FM + l32];
            if (NSEG >= 3)
                bnxt = ws0 ? (ws0[rn] + ws1[rn])
                           : ((l < 32) ? s2[(size_t)rn * FM + l32] : 0.0f);
        }
        sx[g][l] = acur;
        if (NSEG >= 3 && l < 32) sx[g][64 + l] = bcur;
        float a0 = 0.0f, a1 = 0.0f, a2 = 0.0f, a3 = 0.0f;
#pragma unroll
        for (int k = 0; k < IN; k += 16) {
            float4 x0 = *(const float4*)&sx[g][k + 0];
            float4 x1 = *(const float4*)&sx[g][k + 4];
            float4 x2 = *(const float4*)&sx[g][k + 8];
            float4 x3 = *(const float4*)&sx[g][k + 12];
            a0 = fmaf(x0.x, w1r[k + 0], a0);
            a0 = fmaf(x0.y, w1r[k + 1], a0);
            a0 = fmaf(x0.z, w1r[k + 2], a0);
            a0 = fmaf(x0.w, w1r[k + 3], a0);
            a1 = fmaf(x1.x, w1r[k + 4], a1);
            a1 = fmaf(x1.y, w1r[k + 5], a1);
            a1 = fmaf(x1.z, w1r[k + 6], a1);
            a1 = fmaf(x1.w, w1r[k + 7], a1);
            a2 = fmaf(x2.x, w1r[k + 8], a2);
            a2 = fmaf(x2.y, w1r[k + 9], a2);
            a2 = fmaf(x2.z, w1r[k + 10], a2);
            a2 = fmaf(x2.w, w1r[k + 11], a2);
            a3 = fmaf(x3.x, w1r[k + 12], a3);
            a3 = fmaf(x3.y, w1r[k + 13], a3);
            a3 = fmaf(x3.z, w1r[k + 14], a3);
            a3 = fmaf(x3.w, w1r[k + 15], a3);
        }
        float acc = ((a0 + a1) + (a2 + a3)) + b1l;
        sh[g][l] = fmaxf(acc, 0.0f);
        float y0 = 0.0f, y1 = 0.0f;
#pragma unroll
        for (int k = 0; k < 32; k += 8) {
            float4 h0 = *(const float4*)&sh[g][half * 32 + k];
            float4 h1 = *(const float4*)&sh[g][half * 32 + k + 4];
            y0 = fmaf(h0.x, sW2[(half * 32 + k + 0) * FM + l32], y0);
            y0 = fmaf(h0.y, sW2[(half * 32 + k + 1) * FM + l32], y0);
            y0 = fmaf(h0.z, sW2[(half * 32 + k + 2) * FM + l32], y0);
            y0 = fmaf(h0.w, sW2[(half * 32 + k + 3) * FM + l32], y0);
            y1 = fmaf(h1.x, sW2[(half * 32 + k + 4) * FM + l32], y1);
            y1 = fmaf(h1.y, sW2[(half * 32 + k + 5) * FM + l32], y1);
            y1 = fmaf(h1.z, sW2[(half * 32 + k + 6) * FM + l32], y1);
            y1 = fmaf(h1.w, sW2[(half * 32 + k + 7) * FM + l32], y1);
        }
        float y = y0 + y1;
        y += __shfl_xor(y, 32);
        y += b2l;
        float s = warp_sum32(y);
        float mu = s * (1.0f / 32.0f);
        float d = y - mu;
        float v = warp_sum32(d * d);
        if (half == 0) {
            float o = d * rsqrtf(v * (1.0f / 32.0f) + LN_EPS);
            dst[(size_t)row * FM + l32] = o;
            if (dst16) dst16[(size_t)row * FM + l32] = __float2half(o);
        }
        acur = anxt;
        bcur = bnxt;
    }
}

__global__ __launch_bounds__(256) void out_mlp(
    const float* __restrict__ x,
    const float* __restrict__ W1, const float* __restrict__ b1,
    const float* __restrict__ W2, const float* __restrict__ b2,
    float* __restrict__ dst, int nrows) {
    __shared__ float sW2[64 * 16];
    __shared__ float sx[4][FM];
    __shared__ float sh[4][64];
    for (int i = threadIdx.x; i < 64 * 16; i += 256) sW2[i] = W2[i];
    int g = threadIdx.x >> 6, l = threadIdx.x & 63;
    int o = l & 15, q = l >> 4;
    float w1r[FM];
#pragma unroll
    for (int k = 0; k < FM; ++k) w1r[k] = W1[k * 64 + l];
    float b1l = b1[l];
    float b2o = b2[o];
    __syncthreads();
    const int stride = gridDim.x * 4;
    int row = blockIdx.x * 4 + g;
    float xcur = (row < nrows && l < FM) ? x[(size_t)row * FM + l] : 0.0f;
    for (; row < nrows; row += stride) {
        int rn = row + stride;
        float xnxt = (rn < nrows && l < FM) ? x[(size_t)rn * FM + l] : 0.0f;
        if (l < FM) sx[g][l] = xcur;
        float a0 = 0.0f, a1 = 0.0f, a2 = 0.0f, a3 = 0.0f;
#pragma unroll
        for (int k = 0; k < FM; k += 16) {
            float4 x0 = *(const float4*)&sx[g][k + 0];
            float4 x1 = *(const float4*)&sx[g][k + 4];
            float4 x2 = *(const float4*)&sx[g][k + 8];
            float4 x3 = *(const float4*)&sx[g][k + 12];
            a0 = fmaf(x0.x, w1r[k + 0], a0);
            a0 = fmaf(x0.y, w1r[k + 1], a0);
            a0 = fmaf(x0.z, w1r[k + 2], a0);
            a0 = fmaf(x0.w, w1r[k + 3], a0);
            a1 = fmaf(x1.x, w1r[k + 4], a1);
            a1 = fmaf(x1.y, w1r[k + 5], a1);
            a1 = fmaf(x1.z, w1r[k + 6], a1);
            a1 = fmaf(x1.w, w1r[k + 7], a1);
            a2 = fmaf(x2.x, w1r[k + 8], a2);
            a2 = fmaf(x2.y, w1r[k + 9], a2);
            a2 = fmaf(x2.z, w1r[k + 10], a2);
            a2 = fmaf(x2.w, w1r[k + 11], a2);
            a3 = fmaf(x3.x, w1r[k + 12], a3);
            a3 = fmaf(x3.y, w1r[k + 13], a3);
            a3 = fmaf(x3.z, w1r[k + 14], a3);
            a3 = fmaf(x3.w, w1r[k + 15], a3);
        }
        float acc = ((a0 + a1) + (a2 + a3)) + b1l;
        sh[g][l] = fmaxf(acc, 0.0f);
        float y0 = 0.0f, y1 = 0.0f;
#pragma unroll
        for (int k = 0; k < 16; k += 8) {
            int kk = q * 16 + k;
            float4 h0 = *(const float4*)&sh[g][kk];
            float4 h1 = *(const float4*)&sh[g][kk + 4];
            y0 = fmaf(h0.x, sW2[(kk + 0) * 16 + o], y0);
            y0 = fmaf(h0.y, sW2[(kk + 1) * 16 + o], y0);
            y0 = fmaf(h0.z, sW2[(kk + 2) * 16 + o], y0);
            y0 = fmaf(h0.w, sW2[(kk + 3) * 16 + o], y0);
            y1 = fmaf(h1.x, sW2[(kk + 4) * 16 + o], y1);
            y1 = fmaf(h1.y, sW2[(kk + 5) * 16 + o], y1);
            y1 = fmaf(h1.z, sW2[(kk + 6) * 16 + o], y1);
            y1 = fmaf(h1.w, sW2[(kk + 7) * 16 + o], y1);
        }
        float y = y0 + y1;
        y += __shfl_xor(y, 16);
        y += __shfl_xor(y, 32);
        if (q == 0) dst[(size_t)row * 16 + o] = 1.0f / (1.0f + expf(-(y + b2o)));
        xcur = xnxt;
    }
}

// ---------------- launcher ----------------

extern "C" void kernel_launch(void* const* d_in, const int* in_sizes, int n_in,
                              void* d_out, int out_size, void* d_ws, size_t ws_size,
                              hipStream_t stream) {
    const int*   edge_var   = (const int*)d_in[0];
    const int*   edge_const = (const int*)d_in[1];
    const float* edge_val   = (const float*)d_in[2];
    const float* cond       = (const float*)d_in[3];
    const float* pc_W1 = (const float*)d_in[6];
    const float* pc_b1 = (const float*)d_in[7];
    const float* pc_W2 = (const float*)d_in[8];
    const float* pc_b2 = (const float*)d_in[9];
    const float* cu_W1 = (const float*)d_in[10];
    const float* cu_b1 = (const float*)d_in[11];
    const float* cu_W2 = (const float*)d_in[12];
    const float* cu_b2 = (const float*)d_in[13];
    const float* vu_W1 = (const float*)d_in[14];
    const float* vu_b1 = (const float*)d_in[15];
    const float* vu_W2 = (const float*)d_in[16];
    const float* vu_b2 = (const float*)d_in[17];
    const float* out_W1 = (const float*)d_in[18];
    const float* out_b1 = (const float*)d_in[19];
    const float* out_W2 = (const float*)d_in[20];
    const float* out_b2 = (const float*)d_in[21];

    float* ws = (float*)d_ws;
    size_t off = 0;
    auto alloc = [&](size_t nelems) {
        float* p = ws + off;
        off += (nelems + 15) & ~(size_t)15;
        return p;
    };
    float*  emb     = alloc(CONST_COUNT * FM);
    float*  cons    = alloc(CONST_COUNT * FM);
    float*  vars    = alloc(VAR_COUNT * FM);
    float*  msg     = alloc(VAR_COUNT * FM);
    __half* vars16  = (__half*)alloc(VAR_COUNT * FM / 2);
    __half* cons16  = (__half*)alloc(CONST_COUNT * FM / 2);
    int2*   recs_t  = (int2*)alloc((size_t)N_EDGES * 2);
    int2*   recs_c  = (int2*)alloc((size_t)N_EDGES * 2);
    int2*   recs_v  = (int2*)alloc((size_t)N_EDGES * 2);
    int*    lscan   = (int*)alloc((size_t)ABLK * LSTRIDE);
    int*    rlen_T  = (int*)alloc((size_t)NB * AB2);
    int*    btot    = (int*)alloc(2 * NB);
    int*    bb_c    = (int*)alloc(2 * NB + 1);
    int*    bb_v    = (int*)alloc(2 * NB + 1);
    int*    offs_c0 = (int*)alloc(CONST_COUNT + 1);
    int*    offs_c1 = (int*)alloc(CONST_COUNT + 1);
    int*    offs_v0 = (int*)alloc(VAR_COUNT + 1);
    int*    offs_v1 = (int*)alloc(VAR_COUNT + 1);
    float*  wsum_c0 = alloc(CONST_COUNT);
    float*  wsum_c1 = alloc(CONST_COUNT);
    size_t need_bytes = off * sizeof(float);
    bool fast = ws_size >= need_bytes;

    if (fast) {
        // const-direction: dest = edge_const (64 dests/bucket)
        bucket_sort<6><<<ABLK, 256, 0, stream>>>(edge_const, edge_var, edge_val,
                                                 recs_t, lscan, rlen_T, N_EDGES);
        row_sum<<<2 * NB, 256, 0, stream>>>(rlen_T, btot);
        scan_btot<<<1, 256, 0, stream>>>(btot, bb_c, 2 * NB, N_EDGES);
        collect_sort<6, 64><<<2 * NB, 256, 0, stream>>>(
            recs_t, lscan, rlen_T, bb_c, recs_c, offs_c0, offs_c1,
            wsum_c0, wsum_c1, CONST_COUNT);
        // var-direction: dest = edge_var (128 dests/bucket)
        bucket_sort<7><<<ABLK, 256, 0, stream>>>(edge_var, edge_const, edge_val,
                                                 recs_t, lscan, rlen_T, N_EDGES);
        row_sum<<<2 * NB, 256, 0, stream>>>(rlen_T, btot);
        scan_btot<<<1, 256, 0, stream>>>(btot, bb_v, 2 * NB, N_EDGES);
        collect_sort<7, 128><<<2 * NB, 256, 0, stream>>>(
            recs_t, lscan, rlen_T, bb_v, recs_v, offs_v0, offs_v1,
            nullptr, nullptr, VAR_COUNT);
    }

    init_vars<<<(VAR_COUNT * FM + 255) / 256, 256, 0, stream>>>(vars, VAR_COUNT * FM);
    pc_mlp<<<1024, 256, 0, stream>>>(cond, pc_W1, pc_b1, pc_W2, pc_b2, emb, cons,
                                     CONST_COUNT);

    for (int pass = 0; pass < 3; ++pass) {
        if (fast) {
            if (pass == 0) {
                // v2c pass 0: variables == ones -> broadcast wsum (no gather)
                mlp_ln<3><<<1024, 256, 0, stream>>>(cons, emb, nullptr, wsum_c0, wsum_c1,
                                                    cu_W1, cu_b1, cu_W2, cu_b2,
                                                    cons, cons16, CONST_COUNT);
            } else {
                seg_gather16<<<(CONST_COUNT + 15) / 16, 256, 0, stream>>>(
                    offs_c0, offs_c1, recs_c, vars16, msg, CONST_COUNT);
                mlp_ln<3><<<1024, 256, 0, stream>>>(cons, emb, msg, nullptr, nullptr,
                                                    cu_W1, cu_b1, cu_W2, cu_b2,
                                                    cons, cons16, CONST_COUNT);
            }
            seg_gather16<<<(VAR_COUNT + 15) / 16, 256, 0, stream>>>(
                offs_v0, offs_v1, recs_v, cons16, msg, VAR_COUNT);
            mlp_ln<2><<<1024, 256, 0, stream>>>(vars, msg, nullptr, nullptr, nullptr,
                                                vu_W1, vu_b1, vu_W2, vu_b2,
                                                vars, (pass < 2) ? vars16 : nullptr,
                                                VAR_COUNT);
        } else {
            hipMemsetAsync(msg, 0, (size_t)CONST_COUNT * FM * sizeof(float), stream);
            scatter_edges<<<N_EDGES / 8, 256, 0, stream>>>(edge_var, edge_const, edge_val,
                                                           vars, msg, N_EDGES);
            mlp_ln<3><<<1024, 256, 0, stream>>>(cons, emb, msg, nullptr, nullptr,
                                                cu_W1, cu_b1, cu_W2, cu_b2,
                                                cons, nullptr, CONST_COUNT);
            hipMemsetAsync(msg, 0, (size_t)VAR_COUNT * FM * sizeof(float), stream);
            scatter_edges<<<N_EDGES / 8, 256, 0, stream>>>(edge_const, edge_var, edge_val,
                                                           cons, msg, N_EDGES);
            mlp_ln<2><<<1024, 256, 0, stream>>>(vars, msg, nullptr, nullptr, nullptr,
                                                vu_W1, vu_b1, vu_W2, vu_b2,
                                                vars, nullptr, VAR_COUNT);
        }
    }

    out_mlp<<<1024, 256, 0, stream>>>(vars, out_W1, out_b1, out_W2, out_b2,
                                      (float*)d_out, VAR_COUNT);
}